// Round 15
// baseline (3050.485 us; speedup 1.0000x reference)
//
#include <hip/hip_runtime.h>
#include <math.h>
#include <stdint.h>

#define BB 128   // batch
#define SS 128   // seq len
#define EE 300   // embed dim
#define HH 256   // per-direction hidden
#define G4 1024  // 4*HH gate width
#define TT 16    // tagset
#define NEGV -10000.0f
#define START_TAG 14
#define STOP_TAG 15

typedef float f32x4 __attribute__((ext_vector_type(4)));
typedef int   i32x4 __attribute__((ext_vector_type(4)));

__device__ __forceinline__ float sigm(float x) { return 1.0f / (1.0f + expf(-x)); }

__device__ __forceinline__ float4 shfl_xor4(float4 v, int m) {
  float4 r;
  r.x = __shfl_xor(v.x, m); r.y = __shfl_xor(v.y, m);
  r.z = __shfl_xor(v.z, m); r.w = __shfl_xor(v.w, m);
  return r;
}
__device__ __forceinline__ void add4(float4& a, const float4& b) {
  a.x += b.x; a.y += b.y; a.z += b.z; a.w += b.w;
}

// LLC-coherent loads: sc0+sc1 bypass L1/L2 -> device coherent point. Same
// load/store class R5/R10 proved correct (552 us steady, absmax 0).
__device__ __forceinline__ f32x4 load_f4_llc(const float* p) {
  f32x4 v;
  asm volatile("global_load_dwordx4 %0, %1, off sc0 sc1\n\t"
               "s_waitcnt vmcnt(0)"
               : "=v"(v) : "v"(p) : "memory");
  return v;
}
__device__ __forceinline__ void load_tags8(const int* p, i32x4& a, i32x4& b) {
  asm volatile("global_load_dwordx4 %0, %2, off sc0 sc1\n\t"
               "global_load_dwordx4 %1, %2, off offset:16 sc0 sc1\n\t"
               "s_waitcnt vmcnt(0)"
               : "=&v"(a), "=&v"(b) : "v"(p) : "memory");
}

// ---------------- prep: weight transposes + bias folding + tag zero (R10 layouts) ----------------
// WihT[d][e][j] = Wih_d[j][e]           (original j = g*256+u)
// Whh4[d][k][u*4+g] = Whh_d[g*256+u][k] (float4 per (k,u))
// bsum[d][j] = bih_d[j] + bhh_d[j]
__global__ void k_prep(const float* __restrict__ Wih_f, const float* __restrict__ Whh_f,
                       const float* __restrict__ bih_f, const float* __restrict__ bhh_f,
                       const float* __restrict__ Wih_b, const float* __restrict__ Whh_b,
                       const float* __restrict__ bih_b, const float* __restrict__ bhh_b,
                       float* __restrict__ WihT, float* __restrict__ Whh4,
                       float* __restrict__ bsum, int* __restrict__ ctr) {
  int id = blockIdx.x * blockDim.x + threadIdx.x;
  const int N1 = 2 * EE * G4;
  const int N2 = 2 * HH * G4;
  const int N3 = 2 * G4;
  const int N4 = 64 * 256;   // tag regions
  if (id < N1) {
    int d = id / (EE * G4); int r = id % (EE * G4);
    int e = r / G4; int j = r % G4;
    const float* W = d ? Wih_b : Wih_f;
    WihT[id] = W[j * EE + e];
  } else if (id < N1 + N2) {
    int t = id - N1;
    int d = t / (HH * G4); int r = t % (HH * G4);
    int k = r / G4; int q = r % G4; int u = q >> 2; int g = q & 3;
    const float* W = d ? Whh_b : Whh_f;
    Whh4[t] = W[(g * HH + u) * HH + k];
  } else if (id < N1 + N2 + N3) {
    int t = id - N1 - N2;
    int d = t / G4; int j = t % G4;
    bsum[t] = d ? (bih_b[j] + bhh_b[j]) : (bih_f[j] + bhh_f[j]);
  } else if (id < N1 + N2 + N3 + N4) {
    ctr[id - N1 - N2 - N3] = 0;
  }
}

// ---------------- input projection GEMM: MERGED DIRS, 16-row tiles, e-blocked ----------------
// Both directions consume the SAME embedding rows -> one xs stage + one set of
// LDS b128 reads serves both dirs' FMA groups. Halves the LDS-read cost and
// xs staging vs per-dir tiles; W traffic unchanged (each block reads both dirs'
// W rows once, 2.5 GB total from L2/L3). Output float4-per-u (i,f,g,o).
__global__ void k_xproj(const int* __restrict__ sent, const float* __restrict__ emb,
                        const float* __restrict__ WihT, const float* __restrict__ bsum,
                        float4* __restrict__ xp4) {
  __shared__ __align__(16) float xs[16][EE];
  __shared__ int idxs[16];
  int tile = blockIdx.x;          // 0..1023
  int tid = threadIdx.x;
  if (tid < 16) {
    int sb = tile * 16 + tid;
    int s = sb >> 7, b = sb & 127;
    idxs[tid] = sent[b * SS + s];
  }
  __syncthreads();
  for (int t = tid; t < 16 * 75; t += 256) {
    int i = t / 75, e4 = t % 75;
    ((f32x4*)&xs[i][0])[e4] = ((const f32x4*)(emb + (size_t)idxs[i] * EE))[e4];
  }
  __syncthreads();

  const float* WT0 = WihT;                     // d = 0
  const float* WT1 = WihT + (size_t)EE * G4;   // d = 1

  float a0[16], a1[16], a2[16], a3[16];        // d0 gate accs
  float g0[16], g1[16], g2[16], g3[16];        // d1 gate accs
#pragma unroll
  for (int i = 0; i < 16; ++i) {
    a0[i] = 0.f; a1[i] = 0.f; a2[i] = 0.f; a3[i] = 0.f;
    g0[i] = 0.f; g1[i] = 0.f; g2[i] = 0.f; g3[i] = 0.f;
  }

  for (int e4 = 0; e4 < 75; ++e4) {
    f32x4 xv[16];
#pragma unroll
    for (int i = 0; i < 16; ++i)
      xv[i] = *(const f32x4*)&xs[i][e4 * 4];
#pragma unroll
    for (int j = 0; j < 4; ++j) {
      int e = e4 * 4 + j;
      const float* r0 = WT0 + (size_t)e * G4;
      const float* r1 = WT1 + (size_t)e * G4;
      float w00 = r0[tid], w01 = r0[tid + 256], w02 = r0[tid + 512], w03 = r0[tid + 768];
      float w10 = r1[tid], w11 = r1[tid + 256], w12 = r1[tid + 512], w13 = r1[tid + 768];
#pragma unroll
      for (int i = 0; i < 16; ++i) {
        float x = xv[i][j];
        a0[i] += w00 * x; a1[i] += w01 * x; a2[i] += w02 * x; a3[i] += w03 * x;
        g0[i] += w10 * x; g1[i] += w11 * x; g2[i] += w12 * x; g3[i] += w13 * x;
      }
    }
  }

  float b00 = bsum[tid],      b01 = bsum[tid + 256];
  float b02 = bsum[tid + 512], b03 = bsum[tid + 768];
  float b10 = bsum[G4 + tid],      b11 = bsum[G4 + tid + 256];
  float b12 = bsum[G4 + tid + 512], b13 = bsum[G4 + tid + 768];
#pragma unroll
  for (int i = 0; i < 16; ++i) {
    int sb = tile * 16 + i;
    int s = sb >> 7, b = sb & 127;
    xp4[((size_t)(0 * SS + s) * BB + b) * HH + tid] =
        make_float4(a0[i] + b00, a1[i] + b01, a2[i] + b02, a3[i] + b03);
    xp4[((size_t)(1 * SS + s) * BB + b) * HH + tid] =
        make_float4(g0[i] + b10, g1[i] + b11, g2[i] + b12, g3[i] + b13);
  }
}

// ---------------- recurrent LSTM: R5 protocol, 2 co-resident blocks/CU (R10 verbatim) ----------------
__global__ __launch_bounds__(256, 2) void k_recur(
    const float4* __restrict__ xp4, const float4* __restrict__ Wg,
    const float* __restrict__ Wout, const float* __restrict__ h0,
    const float* __restrict__ c0, float* __restrict__ hbuf,
    float* __restrict__ featsP, int* __restrict__ ctr) {
  __shared__ __align__(16) float hshS[4 * 288];  // h staging, kc-swizzled
  __shared__ float hloc[4 * 33];                 // this step's h for feats
  __shared__ float WoL[16 * 33];                 // Wout slice

  int blk = blockIdx.x;
  int d = blk >> 8;
  int bg = (blk >> 3) & 31;
  int sl = blk & 7;
  int bbase = bg * 4;
  int tid = threadIdx.x;
  int u = tid >> 3, kc = tid & 7;
  int uglob = sl * 32 + u;
  int* tagsg = ctr + (d * 32 + bg) * 256 + 64;   // tags[sl] = last finished step + 1

  for (int i = tid; i < 16 * 32; i += 256) {
    int t = i >> 5, uu = i & 31;
    WoL[t * 33 + uu] = Wout[t * 512 + d * HH + sl * 32 + uu];
  }

  // Whh slice -> registers: wreg[kk] = Whh4[d][kc*32+kk][uglob] (i,f,g,o)
  float4 wreg[32];
  {
    const float4* Wd = Wg + (size_t)d * (HH * HH) + (size_t)(kc * 32) * HH + uglob;
#pragma unroll
    for (int kk = 0; kk < 32; ++kk) wreg[kk] = Wd[(size_t)kk * HH];
  }
  int b_own = ((kc & 1) << 1) | ((kc >> 1) & 1);
  float c_reg = c0[((size_t)d * BB + bbase + b_own) * HH + uglob];
  bool up0 = (kc & 1), up1 = (kc & 2);

  int sb = tid >> 6;
  int sk = (tid & 63) * 4;
  int ldoff = sb * 288 + (sk >> 5) * 36 + (sk & 31);

  for (int step = 0; step < SS; ++step) {
    int s = d ? (SS - 1 - step) : step;
    float4 xg = xp4[(((size_t)d * SS + s) * BB + bbase + b_own) * HH + uglob];

    float* ldst = &hshS[ldoff];
    if (step == 0) {
      const float* ps = h0 + ((size_t)d * BB + bbase + sb) * HH + sk;
      *(f32x4*)ldst = *(const f32x4*)ps;
    } else {
      i32x4 ta, tb;
      int m;
      do {
        load_tags8(tagsg, ta, tb);
        int m0 = min(min(ta[0], ta[1]), min(ta[2], ta[3]));
        int m1 = min(min(tb[0], tb[1]), min(tb[2], tb[3]));
        m = min(m0, m1);
      } while (m < step);
      const float* ps = hbuf + ((size_t)((step - 1) % 3) * 2 + d) * BB * HH +
                        (size_t)(bbase + sb) * HH + sk;
      *(f32x4*)ldst = load_f4_llc(ps);
    }
    __syncthreads();

    float4 a[4];
#pragma unroll
    for (int b = 0; b < 4; ++b) a[b] = make_float4(0.f, 0.f, 0.f, 0.f);
#pragma unroll
    for (int kk4 = 0; kk4 < 8; ++kk4) {
      float hvv[4][4];
#pragma unroll
      for (int b = 0; b < 4; ++b)
        *(f32x4*)&hvv[b][0] = *(const f32x4*)&hshS[b * 288 + kc * 36 + kk4 * 4];
#pragma unroll
      for (int j = 0; j < 4; ++j) {
        float4 w = wreg[kk4 * 4 + j];
#pragma unroll
        for (int b = 0; b < 4; ++b) {
          float hj = hvv[b][j];
          a[b].x += w.x * hj; a[b].y += w.y * hj;
          a[b].z += w.z * hj; a[b].w += w.w * hj;
        }
      }
    }

#pragma unroll
    for (int j = 0; j < 2; ++j) {
      float4 snd = up0 ? a[j] : a[j + 2];
      float4 rcv = shfl_xor4(snd, 1);
      if (!up0) add4(a[j], rcv); else add4(a[j + 2], rcv);
    }
    float4 v0 = up0 ? a[2] : a[0];
    float4 v1 = up0 ? a[3] : a[1];
    {
      float4 snd = up1 ? v0 : v1;
      float4 rcv = shfl_xor4(snd, 2);
      if (!up1) add4(v0, rcv); else add4(v1, rcv);
    }
    float4 keep = up1 ? v1 : v0;
    {
      float4 rcv = shfl_xor4(keep, 4);
      add4(keep, rcv);
    }

    float ii = keep.x + xg.x, ff = keep.y + xg.y;
    float gg = keep.z + xg.z, oo = keep.w + xg.w;
    c_reg = sigm(ff) * c_reg + sigm(ii) * tanhf(gg);
    float hn = sigm(oo) * tanhf(c_reg);

    if (kc < 4) {
      __hip_atomic_store(
          &hbuf[((size_t)(step % 3) * 2 + d) * BB * HH + (size_t)(bbase + b_own) * HH + uglob],
          hn, __ATOMIC_RELAXED, __HIP_MEMORY_SCOPE_AGENT);
      hloc[b_own * 33 + u] = hn;
    }
    __syncthreads();   // drains vmcnt(0) per wave -> all h stores at LLC

    if (tid == 0)
      __hip_atomic_store(&tagsg[sl], step + 1, __ATOMIC_RELAXED,
                         __HIP_MEMORY_SCOPE_AGENT);

    {
      int b2 = tid >> 6, t = (tid >> 2) & 15, pr = tid & 3;
      float p = 0.f;
#pragma unroll
      for (int q = 0; q < 8; ++q)
        p += hloc[b2 * 33 + pr * 8 + q] * WoL[t * 33 + pr * 8 + q];
      p += __shfl_xor(p, 1);
      p += __shfl_xor(p, 2);
      if (pr == 0)
        featsP[(((size_t)(d * 8 + sl) * BB + bbase + b2) * SS + s) * TT + t] = p;
    }
  }
}

// ---------------- feats slice reduction ----------------
__global__ void k_fsum(const float* __restrict__ featsP, float* __restrict__ featsF) {
  int b = blockIdx.x;
  int tid = threadIdx.x;
  float acc[8];
#pragma unroll
  for (int j = 0; j < 8; ++j) acc[j] = 0.f;
  for (int dsl = 0; dsl < 16; ++dsl) {
    const float* fp = featsP + ((size_t)dsl * BB + b) * (SS * TT);
#pragma unroll
    for (int j = 0; j < 8; ++j) acc[j] += fp[j * 256 + tid];
  }
  float* fo = featsF + (size_t)b * (SS * TT);
#pragma unroll
  for (int j = 0; j < 8; ++j) fo[j * 256 + tid] = acc[j];
}

// ---------------- Viterbi (backpointers in LDS) ----------------
__global__ void k_viterbi(const float* __restrict__ featsF, const float* __restrict__ b_out,
                          const float* __restrict__ trans, float* __restrict__ out) {
  __shared__ float tr[TT * TT];
  __shared__ unsigned char bpl[16][SS][TT];   // 32 KB
  int tid = threadIdx.x;
  if (tid < TT * TT) tr[tid] = trans[tid];
  __syncthreads();

  int bg = tid >> 4;
  int next = tid & 15;
  int b = blockIdx.x * 16 + bg;
  float fv = (next == START_TAG) ? 0.0f : NEGV;
  float bo = b_out[next];
  const float* fF = featsF + (size_t)b * SS * TT;

  for (int s = 0; s < SS; ++s) {
    float best = -INFINITY; int arg = 0;
#pragma unroll
    for (int prev = 0; prev < TT; ++prev) {
      float fvp = __shfl(fv, prev, 16);
      float cand = fvp + tr[next * TT + prev];
      if (cand > best) { best = cand; arg = prev; }
    }
    float feat = fF[s * TT + next] + bo;
    fv = best + feat;
    bpl[bg][s][next] = (unsigned char)arg;
  }

  float bv = fv + tr[STOP_TAG * TT + next];
  int bi = next;
#pragma unroll
  for (int off = 8; off; off >>= 1) {
    float ov = __shfl_down(bv, off, 16);
    int oi = __shfl_down(bi, off, 16);
    if (ov > bv || (ov == bv && oi < bi)) { bv = ov; bi = oi; }
  }
  if (next == 0) {
    out[b] = bv;
    int tag = bi;
    float* po = out + BB + (size_t)b * SS;
    for (int s = SS - 1; s >= 0; --s) {
      po[s] = (float)tag;
      tag = bpl[bg][s][tag];
    }
  }
}

// ---------------- host ----------------
extern "C" void kernel_launch(void* const* d_in, const int* in_sizes, int n_in,
                              void* d_out, int out_size, void* d_ws, size_t ws_size,
                              hipStream_t stream) {
  const int*   sent  = (const int*)d_in[0];
  const float* emb   = (const float*)d_in[1];
  const float* Wih_f = (const float*)d_in[2];
  const float* Whh_f = (const float*)d_in[3];
  const float* bih_f = (const float*)d_in[4];
  const float* bhh_f = (const float*)d_in[5];
  const float* Wih_b = (const float*)d_in[6];
  const float* Whh_b = (const float*)d_in[7];
  const float* bih_b = (const float*)d_in[8];
  const float* bhh_b = (const float*)d_in[9];
  const float* Wout  = (const float*)d_in[10];
  const float* b_out = (const float*)d_in[11];
  const float* trans = (const float*)d_in[12];
  const float* h0    = (const float*)d_in[13];
  const float* c0    = (const float*)d_in[14];

  float* ws = (float*)d_ws;
  size_t off = 0;
  float* xproj  = ws + off; off += (size_t)2 * SS * BB * G4;          // 33,554,432 fl
  float* WihT   = ws + off; off += (size_t)2 * EE * G4;               //    614,400
  float* Whh4   = ws + off; off += (size_t)2 * HH * G4;               //    524,288
  float* bsum   = ws + off; off += (size_t)2 * G4;                    //      2,048
  float* featsP = ws + off; off += (size_t)16 * BB * SS * TT;         //  4,194,304
  float* featsF = ws + off; off += (size_t)BB * SS * TT;              //    262,144
  float* hbuf   = ws + off; off += (size_t)3 * 2 * BB * HH;           //    196,608
  int*   ctr    = (int*)(ws + off); off += 64 * 256;                  //     64 KB

  const int NPREP = 2 * EE * G4 + 2 * HH * G4 + 2 * G4 + 64 * 256;
  k_prep<<<(NPREP + 255) / 256, 256, 0, stream>>>(Wih_f, Whh_f, bih_f, bhh_f,
                                                  Wih_b, Whh_b, bih_b, bhh_b,
                                                  WihT, Whh4, bsum, ctr);
  k_xproj<<<1024, 256, 0, stream>>>(sent, emb, WihT, bsum, (float4*)xproj);

  {
    const float4* xp4c = (const float4*)xproj;
    const float4* Wgc  = (const float4*)Whh4;
    void* kargs[] = {(void*)&xp4c, (void*)&Wgc, (void*)&Wout, (void*)&h0,
                     (void*)&c0, (void*)&hbuf, (void*)&featsP, (void*)&ctr};
    hipError_t e = hipLaunchCooperativeKernel(k_recur, dim3(512), dim3(256),
                                              kargs, 0, stream);
    if (e != hipSuccess) {
      k_recur<<<512, 256, 0, stream>>>(xp4c, Wgc, Wout, h0, c0, hbuf, featsP, ctr);
    }
  }

  k_fsum<<<BB, 256, 0, stream>>>(featsP, featsF);
  k_viterbi<<<8, 256, 0, stream>>>(featsF, b_out, trans, (float*)d_out);
}

// Round 16
// 831.720 us; speedup vs baseline: 3.6677x; 3.6677x over previous
//
#include <hip/hip_runtime.h>
#include <math.h>
#include <stdint.h>

#define BB 128   // batch
#define SS 128   // seq len
#define EE 300   // embed dim
#define HH 256   // per-direction hidden
#define G4 1024  // 4*HH gate width
#define TT 16    // tagset
#define NEGV -10000.0f
#define START_TAG 14
#define STOP_TAG 15

typedef float f32x4 __attribute__((ext_vector_type(4)));
typedef int   i32x4 __attribute__((ext_vector_type(4)));

__device__ __forceinline__ float sigm(float x) { return 1.0f / (1.0f + expf(-x)); }

__device__ __forceinline__ float4 shfl_xor4(float4 v, int m) {
  float4 r;
  r.x = __shfl_xor(v.x, m); r.y = __shfl_xor(v.y, m);
  r.z = __shfl_xor(v.z, m); r.w = __shfl_xor(v.w, m);
  return r;
}
__device__ __forceinline__ void add4(float4& a, const float4& b) {
  a.x += b.x; a.y += b.y; a.z += b.z; a.w += b.w;
}

// LLC-coherent loads: sc0+sc1 bypass L1/L2 -> device coherent point. Same
// load/store class R5/R10 proved correct (552 us steady, absmax 0).
__device__ __forceinline__ f32x4 load_f4_llc(const float* p) {
  f32x4 v;
  asm volatile("global_load_dwordx4 %0, %1, off sc0 sc1\n\t"
               "s_waitcnt vmcnt(0)"
               : "=v"(v) : "v"(p) : "memory");
  return v;
}
__device__ __forceinline__ void load_tags8(const int* p, i32x4& a, i32x4& b) {
  asm volatile("global_load_dwordx4 %0, %2, off sc0 sc1\n\t"
               "global_load_dwordx4 %1, %2, off offset:16 sc0 sc1\n\t"
               "s_waitcnt vmcnt(0)"
               : "=&v"(a), "=&v"(b) : "v"(p) : "memory");
}

// ---------------- prep: weight transposes + bias folding + tag zero ----------------
__global__ void k_prep(const float* __restrict__ Wih_f, const float* __restrict__ Whh_f,
                       const float* __restrict__ bih_f, const float* __restrict__ bhh_f,
                       const float* __restrict__ Wih_b, const float* __restrict__ Whh_b,
                       const float* __restrict__ bih_b, const float* __restrict__ bhh_b,
                       float* __restrict__ WihT, float* __restrict__ Whh4,
                       float* __restrict__ bsum, int* __restrict__ ctr) {
  int id = blockIdx.x * blockDim.x + threadIdx.x;
  const int N1 = 2 * EE * G4;
  const int N2 = 2 * HH * G4;
  const int N3 = 2 * G4;
  const int N4 = 64 * 256;   // 64 group regions x 256 ints
  if (id < N1) {
    int d = id / (EE * G4); int r = id % (EE * G4);
    int e = r / G4; int j = r % G4;
    const float* W = d ? Wih_b : Wih_f;
    WihT[id] = W[j * EE + e];
  } else if (id < N1 + N2) {
    int t = id - N1;
    int d = t / (HH * G4); int r = t % (HH * G4);
    int k = r / G4; int q = r % G4; int u = q >> 2; int g = q & 3;
    const float* W = d ? Whh_b : Whh_f;
    Whh4[t] = W[(g * HH + u) * HH + k];
  } else if (id < N1 + N2 + N3) {
    int t = id - N1 - N2;
    int d = t / G4; int j = t % G4;
    bsum[t] = d ? (bih_b[j] + bhh_b[j]) : (bih_f[j] + bhh_f[j]);
  } else if (id < N1 + N2 + N3 + N4) {
    ctr[id - N1 - N2 - N3] = 0;
  }
}

// ---------------- input projection GEMM (gathered), e-blocked by 4 ----------------
// launch_bounds(256,2): 256-VGPR budget so the 64 accumulators + xv[16] f32x4
// staging stay in registers (default heuristic budgeted 64 VGPR -> spill).
__global__ __launch_bounds__(256, 2) void k_xproj(
    const int* __restrict__ sent, const float* __restrict__ emb,
    const float* __restrict__ WihT, const float* __restrict__ bsum,
    float4* __restrict__ xp4) {
  __shared__ __align__(16) float xs[16][EE];
  __shared__ int idxs[16];
  int blk = blockIdx.x;
  int d = blk >> 10;
  int tile = blk & 1023;
  int tid = threadIdx.x;
  if (tid < 16) {
    int sb = tile * 16 + tid;
    int s = sb >> 7, b = sb & 127;
    idxs[tid] = sent[b * SS + s];
  }
  __syncthreads();
  for (int t = tid; t < 16 * 75; t += 256) {
    int i = t / 75, e4 = t % 75;
    ((f32x4*)&xs[i][0])[e4] = ((const f32x4*)(emb + (size_t)idxs[i] * EE))[e4];
  }
  __syncthreads();

  const float* WT = WihT + (size_t)d * EE * G4;
  float acc0[16], acc1[16], acc2[16], acc3[16];
#pragma unroll
  for (int i = 0; i < 16; ++i) { acc0[i] = 0.f; acc1[i] = 0.f; acc2[i] = 0.f; acc3[i] = 0.f; }

  for (int e4 = 0; e4 < 75; ++e4) {
    f32x4 xv[16];
#pragma unroll
    for (int i = 0; i < 16; ++i)
      xv[i] = *(const f32x4*)&xs[i][e4 * 4];
    const float* rowb = WT + (size_t)e4 * 4 * G4;
#pragma unroll
    for (int j = 0; j < 4; ++j) {
      const float* row = rowb + (size_t)j * G4;
      float w0 = row[tid];
      float w1 = row[tid + 256];
      float w2 = row[tid + 512];
      float w3 = row[tid + 768];
#pragma unroll
      for (int i = 0; i < 16; ++i) {
        float x = xv[i][j];
        acc0[i] += w0 * x; acc1[i] += w1 * x; acc2[i] += w2 * x; acc3[i] += w3 * x;
      }
    }
  }
  float b0 = bsum[d * G4 + tid];
  float b1 = bsum[d * G4 + tid + 256];
  float b2 = bsum[d * G4 + tid + 512];
  float b3 = bsum[d * G4 + tid + 768];
#pragma unroll
  for (int i = 0; i < 16; ++i) {
    int sb = tile * 16 + i;
    int s = sb >> 7, b = sb & 127;
    xp4[(((size_t)d * SS + s) * BB + b) * HH + tid] =
        make_float4(acc0[i] + b0, acc1[i] + b1, acc2[i] + b2, acc3[i] + b3);
  }
}

// ---------------- recurrent LSTM: R5 protocol, 2 co-resident blocks/CU ----------------
// grid 512: blk = d*256 + bg*8 + sl (bg in [0,32), 4 batches each). 256 thr:
// tid = u*8 + kc. Per-group tag words posted by tid0 after a drain barrier; all
// threads poll the 32B tag line; h via relaxed agent stores + sc0sc1 loads at
// ring slot step%3. Weights stay register-resident at launch_bounds(256,2).
__global__ __launch_bounds__(256, 2) void k_recur(
    const float4* __restrict__ xp4, const float4* __restrict__ Wg,
    const float* __restrict__ Wout, const float* __restrict__ h0,
    const float* __restrict__ c0, float* __restrict__ hbuf,
    float* __restrict__ featsP, int* __restrict__ ctr) {
  __shared__ __align__(16) float hshS[4 * 288];  // h staging, kc-swizzled
  __shared__ float hloc[4 * 33];                 // this step's h for feats
  __shared__ float WoL[16 * 33];                 // Wout slice

  int blk = blockIdx.x;
  int d = blk >> 8;
  int bg = (blk >> 3) & 31;
  int sl = blk & 7;
  int bbase = bg * 4;
  int tid = threadIdx.x;
  int u = tid >> 3, kc = tid & 7;
  int uglob = sl * 32 + u;
  int* tagsg = ctr + (d * 32 + bg) * 256 + 64;   // tags[sl] = last finished step + 1

  for (int i = tid; i < 16 * 32; i += 256) {
    int t = i >> 5, uu = i & 31;
    WoL[t * 33 + uu] = Wout[t * 512 + d * HH + sl * 32 + uu];
  }

  // Whh slice -> registers: wreg[kk] = Whh4[d][kc*32+kk][uglob] (i,f,g,o)
  float4 wreg[32];
  {
    const float4* Wd = Wg + (size_t)d * (HH * HH) + (size_t)(kc * 32) * HH + uglob;
#pragma unroll
    for (int kk = 0; kk < 32; ++kk) wreg[kk] = Wd[(size_t)kk * HH];
  }
  // owner map for 4-batch reduce-scatter over kc (lanes kc and kc^4 duplicate)
  int b_own = ((kc & 1) << 1) | ((kc >> 1) & 1);
  float c_reg = c0[((size_t)d * BB + bbase + b_own) * HH + uglob];
  bool up0 = (kc & 1), up1 = (kc & 2);

  // staging: thread handles (batch sb = tid>>6, k = (tid&63)*4 .. +3)
  int sb = tid >> 6;
  int sk = (tid & 63) * 4;
  int ldoff = sb * 288 + (sk >> 5) * 36 + (sk & 31);

  for (int step = 0; step < SS; ++step) {
    int s = d ? (SS - 1 - step) : step;
    // prefetch gate-input vec (h-independent), in flight during the wait
    float4 xg = xp4[(((size_t)d * SS + s) * BB + bbase + b_own) * HH + uglob];

    // ---- wait + stage h(step-1) ----
    float* ldst = &hshS[ldoff];
    if (step == 0) {
      const float* ps = h0 + ((size_t)d * BB + bbase + sb) * HH + sk;
      *(f32x4*)ldst = *(const f32x4*)ps;
    } else {
      i32x4 ta, tb;
      int m;
      do {
        load_tags8(tagsg, ta, tb);
        int m0 = min(min(ta[0], ta[1]), min(ta[2], ta[3]));
        int m1 = min(min(tb[0], tb[1]), min(tb[2], tb[3]));
        m = min(m0, m1);
      } while (m < step);
      const float* ps = hbuf + ((size_t)((step - 1) % 3) * 2 + d) * BB * HH +
                        (size_t)(bbase + sb) * HH + sk;
      *(f32x4*)ldst = load_f4_llc(ps);
    }
    __syncthreads();

    // ---- gate partials over this thread's 32-k chunk (4 batches) ----
    float4 a[4];
#pragma unroll
    for (int b = 0; b < 4; ++b) a[b] = make_float4(0.f, 0.f, 0.f, 0.f);
#pragma unroll
    for (int kk4 = 0; kk4 < 8; ++kk4) {
      float hvv[4][4];
#pragma unroll
      for (int b = 0; b < 4; ++b)
        *(f32x4*)&hvv[b][0] = *(const f32x4*)&hshS[b * 288 + kc * 36 + kk4 * 4];
#pragma unroll
      for (int j = 0; j < 4; ++j) {
        float4 w = wreg[kk4 * 4 + j];
#pragma unroll
        for (int b = 0; b < 4; ++b) {
          float hj = hvv[b][j];
          a[b].x += w.x * hj; a[b].y += w.y * hj;
          a[b].z += w.z * hj; a[b].w += w.w * hj;
        }
      }
    }

    // ---- reduce-scatter over kc (3 rounds; kc^4 lanes duplicate, benign) ----
#pragma unroll
    for (int j = 0; j < 2; ++j) {
      float4 snd = up0 ? a[j] : a[j + 2];
      float4 rcv = shfl_xor4(snd, 1);
      if (!up0) add4(a[j], rcv); else add4(a[j + 2], rcv);
    }
    float4 v0 = up0 ? a[2] : a[0];
    float4 v1 = up0 ? a[3] : a[1];
    {
      float4 snd = up1 ? v0 : v1;
      float4 rcv = shfl_xor4(snd, 2);
      if (!up1) add4(v0, rcv); else add4(v1, rcv);
    }
    float4 keep = up1 ? v1 : v0;
    {
      float4 rcv = shfl_xor4(keep, 4);
      add4(keep, rcv);
    }

    // ---- nonlinearity + publish ----
    float ii = keep.x + xg.x, ff = keep.y + xg.y;
    float gg = keep.z + xg.z, oo = keep.w + xg.w;
    c_reg = sigm(ff) * c_reg + sigm(ii) * tanhf(gg);
    float hn = sigm(oo) * tanhf(c_reg);

    if (kc < 4) {
      __hip_atomic_store(
          &hbuf[((size_t)(step % 3) * 2 + d) * BB * HH + (size_t)(bbase + b_own) * HH + uglob],
          hn, __ATOMIC_RELAXED, __HIP_MEMORY_SCOPE_AGENT);
      hloc[b_own * 33 + u] = hn;
    }
    __syncthreads();   // drains vmcnt(0) per wave -> all h stores at LLC

    // post the signal ASAP, then feats (overlaps other blocks' spin-exit)
    if (tid == 0)
      __hip_atomic_store(&tagsg[sl], step + 1, __ATOMIC_RELAXED,
                         __HIP_MEMORY_SCOPE_AGENT);

    // feats slice contribution: 256 thr = (b2, t, pr4)
    {
      int b2 = tid >> 6, t = (tid >> 2) & 15, pr = tid & 3;
      float p = 0.f;
#pragma unroll
      for (int q = 0; q < 8; ++q)
        p += hloc[b2 * 33 + pr * 8 + q] * WoL[t * 33 + pr * 8 + q];
      p += __shfl_xor(p, 1);
      p += __shfl_xor(p, 2);
      if (pr == 0)
        featsP[(((size_t)(d * 8 + sl) * BB + bbase + b2) * SS + s) * TT + t] = p;
    }
  }
}

// ---------------- feats slice reduction ----------------
__global__ void k_fsum(const float* __restrict__ featsP, float* __restrict__ featsF) {
  int b = blockIdx.x;
  int tid = threadIdx.x;
  float acc[8];
#pragma unroll
  for (int j = 0; j < 8; ++j) acc[j] = 0.f;
  for (int dsl = 0; dsl < 16; ++dsl) {
    const float* fp = featsP + ((size_t)dsl * BB + b) * (SS * TT);
#pragma unroll
    for (int j = 0; j < 8; ++j) acc[j] += fp[j * 256 + tid];
  }
  float* fo = featsF + (size_t)b * (SS * TT);
#pragma unroll
  for (int j = 0; j < 8; ++j) fo[j * 256 + tid] = acc[j];
}

// ---------------- Viterbi (backpointers in LDS) ----------------
__global__ void k_viterbi(const float* __restrict__ featsF, const float* __restrict__ b_out,
                          const float* __restrict__ trans, float* __restrict__ out) {
  __shared__ float tr[TT * TT];
  __shared__ unsigned char bpl[16][SS][TT];   // 32 KB
  int tid = threadIdx.x;
  if (tid < TT * TT) tr[tid] = trans[tid];
  __syncthreads();

  int bg = tid >> 4;
  int next = tid & 15;
  int b = blockIdx.x * 16 + bg;
  float fv = (next == START_TAG) ? 0.0f : NEGV;
  float bo = b_out[next];
  const float* fF = featsF + (size_t)b * SS * TT;

  for (int s = 0; s < SS; ++s) {
    float best = -INFINITY; int arg = 0;
#pragma unroll
    for (int prev = 0; prev < TT; ++prev) {
      float fvp = __shfl(fv, prev, 16);
      float cand = fvp + tr[next * TT + prev];
      if (cand > best) { best = cand; arg = prev; }
    }
    float feat = fF[s * TT + next] + bo;
    fv = best + feat;
    bpl[bg][s][next] = (unsigned char)arg;
  }

  float bv = fv + tr[STOP_TAG * TT + next];
  int bi = next;
#pragma unroll
  for (int off = 8; off; off >>= 1) {
    float ov = __shfl_down(bv, off, 16);
    int oi = __shfl_down(bi, off, 16);
    if (ov > bv || (ov == bv && oi < bi)) { bv = ov; bi = oi; }
  }
  if (next == 0) {
    out[b] = bv;
    int tag = bi;
    float* po = out + BB + (size_t)b * SS;
    for (int s = SS - 1; s >= 0; --s) {
      po[s] = (float)tag;
      tag = bpl[bg][s][tag];
    }
  }
}

// ---------------- host ----------------
extern "C" void kernel_launch(void* const* d_in, const int* in_sizes, int n_in,
                              void* d_out, int out_size, void* d_ws, size_t ws_size,
                              hipStream_t stream) {
  const int*   sent  = (const int*)d_in[0];
  const float* emb   = (const float*)d_in[1];
  const float* Wih_f = (const float*)d_in[2];
  const float* Whh_f = (const float*)d_in[3];
  const float* bih_f = (const float*)d_in[4];
  const float* bhh_f = (const float*)d_in[5];
  const float* Wih_b = (const float*)d_in[6];
  const float* Whh_b = (const float*)d_in[7];
  const float* bih_b = (const float*)d_in[8];
  const float* bhh_b = (const float*)d_in[9];
  const float* Wout  = (const float*)d_in[10];
  const float* b_out = (const float*)d_in[11];
  const float* trans = (const float*)d_in[12];
  const float* h0    = (const float*)d_in[13];
  const float* c0    = (const float*)d_in[14];

  float* ws = (float*)d_ws;
  size_t off = 0;
  float* xproj  = ws + off; off += (size_t)2 * SS * BB * G4;          // 33,554,432 fl
  float* WihT   = ws + off; off += (size_t)2 * EE * G4;               //    614,400
  float* Whh4   = ws + off; off += (size_t)2 * HH * G4;               //    524,288
  float* bsum   = ws + off; off += (size_t)2 * G4;                    //      2,048
  float* featsP = ws + off; off += (size_t)16 * BB * SS * TT;         //  4,194,304
  float* featsF = ws + off; off += (size_t)BB * SS * TT;              //    262,144
  float* hbuf   = ws + off; off += (size_t)3 * 2 * BB * HH;           //    196,608
  int*   ctr    = (int*)(ws + off); off += 64 * 256;                  //     64 KB

  const int NPREP = 2 * EE * G4 + 2 * HH * G4 + 2 * G4 + 64 * 256;
  k_prep<<<(NPREP + 255) / 256, 256, 0, stream>>>(Wih_f, Whh_f, bih_f, bhh_f,
                                                  Wih_b, Whh_b, bih_b, bhh_b,
                                                  WihT, Whh4, bsum, ctr);
  k_xproj<<<2048, 256, 0, stream>>>(sent, emb, WihT, bsum, (float4*)xproj);

  {
    const float4* xp4c = (const float4*)xproj;
    const float4* Wgc  = (const float4*)Whh4;
    void* kargs[] = {(void*)&xp4c, (void*)&Wgc, (void*)&Wout, (void*)&h0,
                     (void*)&c0, (void*)&hbuf, (void*)&featsP, (void*)&ctr};
    hipError_t e = hipLaunchCooperativeKernel(k_recur, dim3(512), dim3(256),
                                              kargs, 0, stream);
    if (e != hipSuccess) {
      // plain launch: 512 blocks fit 2/CU at our VGPR/LDS usage -> all resident
      k_recur<<<512, 256, 0, stream>>>(xp4c, Wgc, Wout, h0, c0, hbuf, featsP, ctr);
    }
  }

  k_fsum<<<BB, 256, 0, stream>>>(featsP, featsF);
  k_viterbi<<<8, 256, 0, stream>>>(featsF, b_out, trans, (float*)d_out);
}

// Round 17
// 824.905 us; speedup vs baseline: 3.6980x; 1.0083x over previous
//
#include <hip/hip_runtime.h>
#include <math.h>
#include <stdint.h>

#define BB 128   // batch
#define SS 128   // seq len
#define EE 300   // embed dim
#define HH 256   // per-direction hidden
#define G4 1024  // 4*HH gate width
#define TT 16    // tagset
#define NEGV -10000.0f
#define START_TAG 14
#define STOP_TAG 15

typedef float f32x4 __attribute__((ext_vector_type(4)));
typedef int   i32x4 __attribute__((ext_vector_type(4)));

__device__ __forceinline__ float sigm(float x) { return 1.0f / (1.0f + expf(-x)); }

__device__ __forceinline__ float4 shfl_xor4(float4 v, int m) {
  float4 r;
  r.x = __shfl_xor(v.x, m); r.y = __shfl_xor(v.y, m);
  r.z = __shfl_xor(v.z, m); r.w = __shfl_xor(v.w, m);
  return r;
}
__device__ __forceinline__ void add4(float4& a, const float4& b) {
  a.x += b.x; a.y += b.y; a.z += b.z; a.w += b.w;
}

// LLC-coherent loads: sc0+sc1 bypass L1/L2 -> device coherent point. Same
// load/store class R5/R10 proved correct (552 us steady, absmax 0).
__device__ __forceinline__ f32x4 load_f4_llc(const float* p) {
  f32x4 v;
  asm volatile("global_load_dwordx4 %0, %1, off sc0 sc1\n\t"
               "s_waitcnt vmcnt(0)"
               : "=v"(v) : "v"(p) : "memory");
  return v;
}
__device__ __forceinline__ void load_tags8(const int* p, i32x4& a, i32x4& b) {
  asm volatile("global_load_dwordx4 %0, %2, off sc0 sc1\n\t"
               "global_load_dwordx4 %1, %2, off offset:16 sc0 sc1\n\t"
               "s_waitcnt vmcnt(0)"
               : "=&v"(a), "=&v"(b) : "v"(p) : "memory");
}

// ---------------- prep: weight transposes + bias folding + tag zero ----------------
__global__ void k_prep(const float* __restrict__ Wih_f, const float* __restrict__ Whh_f,
                       const float* __restrict__ bih_f, const float* __restrict__ bhh_f,
                       const float* __restrict__ Wih_b, const float* __restrict__ Whh_b,
                       const float* __restrict__ bih_b, const float* __restrict__ bhh_b,
                       float* __restrict__ WihT, float* __restrict__ Whh4,
                       float* __restrict__ bsum, int* __restrict__ ctr) {
  int id = blockIdx.x * blockDim.x + threadIdx.x;
  const int N1 = 2 * EE * G4;
  const int N2 = 2 * HH * G4;
  const int N3 = 2 * G4;
  const int N4 = 64 * 256;   // 64 group regions x 256 ints
  if (id < N1) {
    int d = id / (EE * G4); int r = id % (EE * G4);
    int e = r / G4; int j = r % G4;
    const float* W = d ? Wih_b : Wih_f;
    WihT[id] = W[j * EE + e];
  } else if (id < N1 + N2) {
    int t = id - N1;
    int d = t / (HH * G4); int r = t % (HH * G4);
    int k = r / G4; int q = r % G4; int u = q >> 2; int g = q & 3;
    const float* W = d ? Whh_b : Whh_f;
    Whh4[t] = W[(g * HH + u) * HH + k];
  } else if (id < N1 + N2 + N3) {
    int t = id - N1 - N2;
    int d = t / G4; int j = t % G4;
    bsum[t] = d ? (bih_b[j] + bhh_b[j]) : (bih_f[j] + bhh_f[j]);
  } else if (id < N1 + N2 + N3 + N4) {
    ctr[id - N1 - N2 - N3] = 0;
  }
}

// ---------------- input projection GEMM: MERGED DIRS, 16-row tiles, e-blocked ----------------
// Both directions consume the SAME embedding rows -> one xs stage + one set of
// LDS b128 reads serves both dirs (halves LDS-pipe time: 192 -> 96 us device-
// wide, below the 128 us FMA floor). launch_bounds(256,2) declares the 256-VGPR
// budget so the 128 scalar accumulators + xv[16] stay in registers — R15 ran
// this exact body WITHOUT the declaration, got a 64-VGPR budget, and spilled
// (13 GB scratch traffic). VGPR_Count must read ~200-230, NOT 64.
__global__ __launch_bounds__(256, 2) void k_xproj(
    const int* __restrict__ sent, const float* __restrict__ emb,
    const float* __restrict__ WihT, const float* __restrict__ bsum,
    float4* __restrict__ xp4) {
  __shared__ __align__(16) float xs[16][EE];
  __shared__ int idxs[16];
  int tile = blockIdx.x;          // 0..1023
  int tid = threadIdx.x;
  if (tid < 16) {
    int sb = tile * 16 + tid;
    int s = sb >> 7, b = sb & 127;
    idxs[tid] = sent[b * SS + s];
  }
  __syncthreads();
  for (int t = tid; t < 16 * 75; t += 256) {
    int i = t / 75, e4 = t % 75;
    ((f32x4*)&xs[i][0])[e4] = ((const f32x4*)(emb + (size_t)idxs[i] * EE))[e4];
  }
  __syncthreads();

  const float* WT0 = WihT;                     // d = 0
  const float* WT1 = WihT + (size_t)EE * G4;   // d = 1

  float a0[16], a1[16], a2[16], a3[16];        // d0 gate accs
  float g0[16], g1[16], g2[16], g3[16];        // d1 gate accs
#pragma unroll
  for (int i = 0; i < 16; ++i) {
    a0[i] = 0.f; a1[i] = 0.f; a2[i] = 0.f; a3[i] = 0.f;
    g0[i] = 0.f; g1[i] = 0.f; g2[i] = 0.f; g3[i] = 0.f;
  }

  for (int e4 = 0; e4 < 75; ++e4) {
    f32x4 xv[16];
#pragma unroll
    for (int i = 0; i < 16; ++i)
      xv[i] = *(const f32x4*)&xs[i][e4 * 4];
#pragma unroll
    for (int j = 0; j < 4; ++j) {
      int e = e4 * 4 + j;
      const float* r0 = WT0 + (size_t)e * G4;
      const float* r1 = WT1 + (size_t)e * G4;
      float w00 = r0[tid], w01 = r0[tid + 256], w02 = r0[tid + 512], w03 = r0[tid + 768];
      float w10 = r1[tid], w11 = r1[tid + 256], w12 = r1[tid + 512], w13 = r1[tid + 768];
#pragma unroll
      for (int i = 0; i < 16; ++i) {
        float x = xv[i][j];
        a0[i] += w00 * x; a1[i] += w01 * x; a2[i] += w02 * x; a3[i] += w03 * x;
        g0[i] += w10 * x; g1[i] += w11 * x; g2[i] += w12 * x; g3[i] += w13 * x;
      }
    }
  }

  float b00 = bsum[tid],       b01 = bsum[tid + 256];
  float b02 = bsum[tid + 512], b03 = bsum[tid + 768];
  float b10 = bsum[G4 + tid],       b11 = bsum[G4 + tid + 256];
  float b12 = bsum[G4 + tid + 512], b13 = bsum[G4 + tid + 768];
#pragma unroll
  for (int i = 0; i < 16; ++i) {
    int sb = tile * 16 + i;
    int s = sb >> 7, b = sb & 127;
    xp4[((size_t)(0 * SS + s) * BB + b) * HH + tid] =
        make_float4(a0[i] + b00, a1[i] + b01, a2[i] + b02, a3[i] + b03);
    xp4[((size_t)(1 * SS + s) * BB + b) * HH + tid] =
        make_float4(g0[i] + b10, g1[i] + b11, g2[i] + b12, g3[i] + b13);
  }
}

// ---------------- recurrent LSTM: R5 protocol, 2 co-resident blocks/CU (R16 verbatim) ----------------
__global__ __launch_bounds__(256, 2) void k_recur(
    const float4* __restrict__ xp4, const float4* __restrict__ Wg,
    const float* __restrict__ Wout, const float* __restrict__ h0,
    const float* __restrict__ c0, float* __restrict__ hbuf,
    float* __restrict__ featsP, int* __restrict__ ctr) {
  __shared__ __align__(16) float hshS[4 * 288];  // h staging, kc-swizzled
  __shared__ float hloc[4 * 33];                 // this step's h for feats
  __shared__ float WoL[16 * 33];                 // Wout slice

  int blk = blockIdx.x;
  int d = blk >> 8;
  int bg = (blk >> 3) & 31;
  int sl = blk & 7;
  int bbase = bg * 4;
  int tid = threadIdx.x;
  int u = tid >> 3, kc = tid & 7;
  int uglob = sl * 32 + u;
  int* tagsg = ctr + (d * 32 + bg) * 256 + 64;   // tags[sl] = last finished step + 1

  for (int i = tid; i < 16 * 32; i += 256) {
    int t = i >> 5, uu = i & 31;
    WoL[t * 33 + uu] = Wout[t * 512 + d * HH + sl * 32 + uu];
  }

  // Whh slice -> registers: wreg[kk] = Whh4[d][kc*32+kk][uglob] (i,f,g,o)
  float4 wreg[32];
  {
    const float4* Wd = Wg + (size_t)d * (HH * HH) + (size_t)(kc * 32) * HH + uglob;
#pragma unroll
    for (int kk = 0; kk < 32; ++kk) wreg[kk] = Wd[(size_t)kk * HH];
  }
  int b_own = ((kc & 1) << 1) | ((kc >> 1) & 1);
  float c_reg = c0[((size_t)d * BB + bbase + b_own) * HH + uglob];
  bool up0 = (kc & 1), up1 = (kc & 2);

  int sb = tid >> 6;
  int sk = (tid & 63) * 4;
  int ldoff = sb * 288 + (sk >> 5) * 36 + (sk & 31);

  for (int step = 0; step < SS; ++step) {
    int s = d ? (SS - 1 - step) : step;
    float4 xg = xp4[(((size_t)d * SS + s) * BB + bbase + b_own) * HH + uglob];

    float* ldst = &hshS[ldoff];
    if (step == 0) {
      const float* ps = h0 + ((size_t)d * BB + bbase + sb) * HH + sk;
      *(f32x4*)ldst = *(const f32x4*)ps;
    } else {
      i32x4 ta, tb;
      int m;
      do {
        load_tags8(tagsg, ta, tb);
        int m0 = min(min(ta[0], ta[1]), min(ta[2], ta[3]));
        int m1 = min(min(tb[0], tb[1]), min(tb[2], tb[3]));
        m = min(m0, m1);
      } while (m < step);
      const float* ps = hbuf + ((size_t)((step - 1) % 3) * 2 + d) * BB * HH +
                        (size_t)(bbase + sb) * HH + sk;
      *(f32x4*)ldst = load_f4_llc(ps);
    }
    __syncthreads();

    float4 a[4];
#pragma unroll
    for (int b = 0; b < 4; ++b) a[b] = make_float4(0.f, 0.f, 0.f, 0.f);
#pragma unroll
    for (int kk4 = 0; kk4 < 8; ++kk4) {
      float hvv[4][4];
#pragma unroll
      for (int b = 0; b < 4; ++b)
        *(f32x4*)&hvv[b][0] = *(const f32x4*)&hshS[b * 288 + kc * 36 + kk4 * 4];
#pragma unroll
      for (int j = 0; j < 4; ++j) {
        float4 w = wreg[kk4 * 4 + j];
#pragma unroll
        for (int b = 0; b < 4; ++b) {
          float hj = hvv[b][j];
          a[b].x += w.x * hj; a[b].y += w.y * hj;
          a[b].z += w.z * hj; a[b].w += w.w * hj;
        }
      }
    }

#pragma unroll
    for (int j = 0; j < 2; ++j) {
      float4 snd = up0 ? a[j] : a[j + 2];
      float4 rcv = shfl_xor4(snd, 1);
      if (!up0) add4(a[j], rcv); else add4(a[j + 2], rcv);
    }
    float4 v0 = up0 ? a[2] : a[0];
    float4 v1 = up0 ? a[3] : a[1];
    {
      float4 snd = up1 ? v0 : v1;
      float4 rcv = shfl_xor4(snd, 2);
      if (!up1) add4(v0, rcv); else add4(v1, rcv);
    }
    float4 keep = up1 ? v1 : v0;
    {
      float4 rcv = shfl_xor4(keep, 4);
      add4(keep, rcv);
    }

    float ii = keep.x + xg.x, ff = keep.y + xg.y;
    float gg = keep.z + xg.z, oo = keep.w + xg.w;
    c_reg = sigm(ff) * c_reg + sigm(ii) * tanhf(gg);
    float hn = sigm(oo) * tanhf(c_reg);

    if (kc < 4) {
      __hip_atomic_store(
          &hbuf[((size_t)(step % 3) * 2 + d) * BB * HH + (size_t)(bbase + b_own) * HH + uglob],
          hn, __ATOMIC_RELAXED, __HIP_MEMORY_SCOPE_AGENT);
      hloc[b_own * 33 + u] = hn;
    }
    __syncthreads();   // drains vmcnt(0) per wave -> all h stores at LLC

    if (tid == 0)
      __hip_atomic_store(&tagsg[sl], step + 1, __ATOMIC_RELAXED,
                         __HIP_MEMORY_SCOPE_AGENT);

    {
      int b2 = tid >> 6, t = (tid >> 2) & 15, pr = tid & 3;
      float p = 0.f;
#pragma unroll
      for (int q = 0; q < 8; ++q)
        p += hloc[b2 * 33 + pr * 8 + q] * WoL[t * 33 + pr * 8 + q];
      p += __shfl_xor(p, 1);
      p += __shfl_xor(p, 2);
      if (pr == 0)
        featsP[(((size_t)(d * 8 + sl) * BB + bbase + b2) * SS + s) * TT + t] = p;
    }
  }
}

// ---------------- feats slice reduction ----------------
__global__ void k_fsum(const float* __restrict__ featsP, float* __restrict__ featsF) {
  int b = blockIdx.x;
  int tid = threadIdx.x;
  float acc[8];
#pragma unroll
  for (int j = 0; j < 8; ++j) acc[j] = 0.f;
  for (int dsl = 0; dsl < 16; ++dsl) {
    const float* fp = featsP + ((size_t)dsl * BB + b) * (SS * TT);
#pragma unroll
    for (int j = 0; j < 8; ++j) acc[j] += fp[j * 256 + tid];
  }
  float* fo = featsF + (size_t)b * (SS * TT);
#pragma unroll
  for (int j = 0; j < 8; ++j) fo[j * 256 + tid] = acc[j];
}

// ---------------- Viterbi (backpointers in LDS) ----------------
__global__ void k_viterbi(const float* __restrict__ featsF, const float* __restrict__ b_out,
                          const float* __restrict__ trans, float* __restrict__ out) {
  __shared__ float tr[TT * TT];
  __shared__ unsigned char bpl[16][SS][TT];   // 32 KB
  int tid = threadIdx.x;
  if (tid < TT * TT) tr[tid] = trans[tid];
  __syncthreads();

  int bg = tid >> 4;
  int next = tid & 15;
  int b = blockIdx.x * 16 + bg;
  float fv = (next == START_TAG) ? 0.0f : NEGV;
  float bo = b_out[next];
  const float* fF = featsF + (size_t)b * SS * TT;

  for (int s = 0; s < SS; ++s) {
    float best = -INFINITY; int arg = 0;
#pragma unroll
    for (int prev = 0; prev < TT; ++prev) {
      float fvp = __shfl(fv, prev, 16);
      float cand = fvp + tr[next * TT + prev];
      if (cand > best) { best = cand; arg = prev; }
    }
    float feat = fF[s * TT + next] + bo;
    fv = best + feat;
    bpl[bg][s][next] = (unsigned char)arg;
  }

  float bv = fv + tr[STOP_TAG * TT + next];
  int bi = next;
#pragma unroll
  for (int off = 8; off; off >>= 1) {
    float ov = __shfl_down(bv, off, 16);
    int oi = __shfl_down(bi, off, 16);
    if (ov > bv || (ov == bv && oi < bi)) { bv = ov; bi = oi; }
  }
  if (next == 0) {
    out[b] = bv;
    int tag = bi;
    float* po = out + BB + (size_t)b * SS;
    for (int s = SS - 1; s >= 0; --s) {
      po[s] = (float)tag;
      tag = bpl[bg][s][tag];
    }
  }
}

// ---------------- host ----------------
extern "C" void kernel_launch(void* const* d_in, const int* in_sizes, int n_in,
                              void* d_out, int out_size, void* d_ws, size_t ws_size,
                              hipStream_t stream) {
  const int*   sent  = (const int*)d_in[0];
  const float* emb   = (const float*)d_in[1];
  const float* Wih_f = (const float*)d_in[2];
  const float* Whh_f = (const float*)d_in[3];
  const float* bih_f = (const float*)d_in[4];
  const float* bhh_f = (const float*)d_in[5];
  const float* Wih_b = (const float*)d_in[6];
  const float* Whh_b = (const float*)d_in[7];
  const float* bih_b = (const float*)d_in[8];
  const float* bhh_b = (const float*)d_in[9];
  const float* Wout  = (const float*)d_in[10];
  const float* b_out = (const float*)d_in[11];
  const float* trans = (const float*)d_in[12];
  const float* h0    = (const float*)d_in[13];
  const float* c0    = (const float*)d_in[14];

  float* ws = (float*)d_ws;
  size_t off = 0;
  float* xproj  = ws + off; off += (size_t)2 * SS * BB * G4;          // 33,554,432 fl
  float* WihT   = ws + off; off += (size_t)2 * EE * G4;               //    614,400
  float* Whh4   = ws + off; off += (size_t)2 * HH * G4;               //    524,288
  float* bsum   = ws + off; off += (size_t)2 * G4;                    //      2,048
  float* featsP = ws + off; off += (size_t)16 * BB * SS * TT;         //  4,194,304
  float* featsF = ws + off; off += (size_t)BB * SS * TT;              //    262,144
  float* hbuf   = ws + off; off += (size_t)3 * 2 * BB * HH;           //    196,608
  int*   ctr    = (int*)(ws + off); off += 64 * 256;                  //     64 KB

  const int NPREP = 2 * EE * G4 + 2 * HH * G4 + 2 * G4 + 64 * 256;
  k_prep<<<(NPREP + 255) / 256, 256, 0, stream>>>(Wih_f, Whh_f, bih_f, bhh_f,
                                                  Wih_b, Whh_b, bih_b, bhh_b,
                                                  WihT, Whh4, bsum, ctr);
  k_xproj<<<1024, 256, 0, stream>>>(sent, emb, WihT, bsum, (float4*)xproj);

  {
    const float4* xp4c = (const float4*)xproj;
    const float4* Wgc  = (const float4*)Whh4;
    void* kargs[] = {(void*)&xp4c, (void*)&Wgc, (void*)&Wout, (void*)&h0,
                     (void*)&c0, (void*)&hbuf, (void*)&featsP, (void*)&ctr};
    hipError_t e = hipLaunchCooperativeKernel(k_recur, dim3(512), dim3(256),
                                              kargs, 0, stream);
    if (e != hipSuccess) {
      k_recur<<<512, 256, 0, stream>>>(xp4c, Wgc, Wout, h0, c0, hbuf, featsP, ctr);
    }
  }

  k_fsum<<<BB, 256, 0, stream>>>(featsP, featsF);
  k_viterbi<<<8, 256, 0, stream>>>(featsF, b_out, trans, (float*)d_out);
}

// Round 18
// 805.014 us; speedup vs baseline: 3.7894x; 1.0247x over previous
//
#include <hip/hip_runtime.h>
#include <math.h>
#include <stdint.h>

#define BB 128   // batch
#define SS 128   // seq len
#define EE 300   // embed dim
#define HH 256   // per-direction hidden
#define G4 1024  // 4*HH gate width
#define TT 16    // tagset
#define NEGV -10000.0f
#define START_TAG 14
#define STOP_TAG 15

typedef float f32x4 __attribute__((ext_vector_type(4)));
typedef int   i32x4 __attribute__((ext_vector_type(4)));

__device__ __forceinline__ float sigm(float x) { return 1.0f / (1.0f + expf(-x)); }

__device__ __forceinline__ float4 shfl_xor4(float4 v, int m) {
  float4 r;
  r.x = __shfl_xor(v.x, m); r.y = __shfl_xor(v.y, m);
  r.z = __shfl_xor(v.z, m); r.w = __shfl_xor(v.w, m);
  return r;
}
__device__ __forceinline__ void add4(float4& a, const float4& b) {
  a.x += b.x; a.y += b.y; a.z += b.z; a.w += b.w;
}

// LLC-coherent loads: sc0+sc1 bypass L1/L2 -> device coherent point. Same
// load/store class R5/R10/R16/R17 proved correct (absmax 0 across 8 rounds).
__device__ __forceinline__ f32x4 load_f4_llc(const float* p) {
  f32x4 v;
  asm volatile("global_load_dwordx4 %0, %1, off sc0 sc1\n\t"
               "s_waitcnt vmcnt(0)"
               : "=v"(v) : "v"(p) : "memory");
  return v;
}
__device__ __forceinline__ void load_tags8(const int* p, i32x4& a, i32x4& b) {
  asm volatile("global_load_dwordx4 %0, %2, off sc0 sc1\n\t"
               "global_load_dwordx4 %1, %2, off offset:16 sc0 sc1\n\t"
               "s_waitcnt vmcnt(0)"
               : "=&v"(a), "=&v"(b) : "v"(p) : "memory");
}

// ---------------- prep: weight transposes + bias folding + tag zero ----------------
__global__ void k_prep(const float* __restrict__ Wih_f, const float* __restrict__ Whh_f,
                       const float* __restrict__ bih_f, const float* __restrict__ bhh_f,
                       const float* __restrict__ Wih_b, const float* __restrict__ Whh_b,
                       const float* __restrict__ bih_b, const float* __restrict__ bhh_b,
                       float* __restrict__ WihT, float* __restrict__ Whh4,
                       float* __restrict__ bsum, int* __restrict__ ctr) {
  int id = blockIdx.x * blockDim.x + threadIdx.x;
  const int N1 = 2 * EE * G4;
  const int N2 = 2 * HH * G4;
  const int N3 = 2 * G4;
  const int N4 = 64 * 256;   // 64 group regions x 256 ints
  if (id < N1) {
    int d = id / (EE * G4); int r = id % (EE * G4);
    int e = r / G4; int j = r % G4;
    const float* W = d ? Wih_b : Wih_f;
    WihT[id] = W[j * EE + e];
  } else if (id < N1 + N2) {
    int t = id - N1;
    int d = t / (HH * G4); int r = t % (HH * G4);
    int k = r / G4; int q = r % G4; int u = q >> 2; int g = q & 3;
    const float* W = d ? Whh_b : Whh_f;
    Whh4[t] = W[(g * HH + u) * HH + k];
  } else if (id < N1 + N2 + N3) {
    int t = id - N1 - N2;
    int d = t / G4; int j = t % G4;
    bsum[t] = d ? (bih_b[j] + bhh_b[j]) : (bih_f[j] + bhh_f[j]);
  } else if (id < N1 + N2 + N3 + N4) {
    ctr[id - N1 - N2 - N3] = 0;
  }
}

// ---------------- input projection GEMM: MERGED DIRS, 16-row tiles, e-blocked ----------------
// One xs stage + one set of LDS b128 reads serves both dirs. launch_bounds(256,2)
// declares the 256-VGPR budget so the 128 scalar accumulators + xv[16] stay in
// registers (without it the heuristic budgets 64 VGPR and spills — R15: 13 GB
// scratch traffic).
__global__ __launch_bounds__(256, 2) void k_xproj(
    const int* __restrict__ sent, const float* __restrict__ emb,
    const float* __restrict__ WihT, const float* __restrict__ bsum,
    float4* __restrict__ xp4) {
  __shared__ __align__(16) float xs[16][EE];
  __shared__ int idxs[16];
  int tile = blockIdx.x;          // 0..1023
  int tid = threadIdx.x;
  if (tid < 16) {
    int sb = tile * 16 + tid;
    int s = sb >> 7, b = sb & 127;
    idxs[tid] = sent[b * SS + s];
  }
  __syncthreads();
  for (int t = tid; t < 16 * 75; t += 256) {
    int i = t / 75, e4 = t % 75;
    ((f32x4*)&xs[i][0])[e4] = ((const f32x4*)(emb + (size_t)idxs[i] * EE))[e4];
  }
  __syncthreads();

  const float* WT0 = WihT;                     // d = 0
  const float* WT1 = WihT + (size_t)EE * G4;   // d = 1

  float a0[16], a1[16], a2[16], a3[16];        // d0 gate accs
  float g0[16], g1[16], g2[16], g3[16];        // d1 gate accs
#pragma unroll
  for (int i = 0; i < 16; ++i) {
    a0[i] = 0.f; a1[i] = 0.f; a2[i] = 0.f; a3[i] = 0.f;
    g0[i] = 0.f; g1[i] = 0.f; g2[i] = 0.f; g3[i] = 0.f;
  }

  for (int e4 = 0; e4 < 75; ++e4) {
    f32x4 xv[16];
#pragma unroll
    for (int i = 0; i < 16; ++i)
      xv[i] = *(const f32x4*)&xs[i][e4 * 4];
#pragma unroll
    for (int j = 0; j < 4; ++j) {
      int e = e4 * 4 + j;
      const float* r0 = WT0 + (size_t)e * G4;
      const float* r1 = WT1 + (size_t)e * G4;
      float w00 = r0[tid], w01 = r0[tid + 256], w02 = r0[tid + 512], w03 = r0[tid + 768];
      float w10 = r1[tid], w11 = r1[tid + 256], w12 = r1[tid + 512], w13 = r1[tid + 768];
#pragma unroll
      for (int i = 0; i < 16; ++i) {
        float x = xv[i][j];
        a0[i] += w00 * x; a1[i] += w01 * x; a2[i] += w02 * x; a3[i] += w03 * x;
        g0[i] += w10 * x; g1[i] += w11 * x; g2[i] += w12 * x; g3[i] += w13 * x;
      }
    }
  }

  float b00 = bsum[tid],       b01 = bsum[tid + 256];
  float b02 = bsum[tid + 512], b03 = bsum[tid + 768];
  float b10 = bsum[G4 + tid],       b11 = bsum[G4 + tid + 256];
  float b12 = bsum[G4 + tid + 512], b13 = bsum[G4 + tid + 768];
#pragma unroll
  for (int i = 0; i < 16; ++i) {
    int sb = tile * 16 + i;
    int s = sb >> 7, b = sb & 127;
    xp4[((size_t)(0 * SS + s) * BB + b) * HH + tid] =
        make_float4(a0[i] + b00, a1[i] + b01, a2[i] + b02, a3[i] + b03);
    xp4[((size_t)(1 * SS + s) * BB + b) * HH + tid] =
        make_float4(g0[i] + b10, g1[i] + b11, g2[i] + b12, g3[i] + b13);
  }
}

// ---------------- recurrent LSTM: R5 protocol, 2 co-resident blocks/CU ----------------
// grid 512 PLAIN launch: blk = d*256 + bg*8 + sl (bg in [0,32), 4 batches).
// Co-residency of all 512 blocks is guaranteed by capacity arithmetic
// (launch_bounds(256,2), 128 VGPR, 7.6 KB LDS -> exactly 2 blocks/CU x 256 CU),
// independent of dispatch order; spins are bounded-traffic tag polls.
__global__ __launch_bounds__(256, 2) void k_recur(
    const float4* __restrict__ xp4, const float4* __restrict__ Wg,
    const float* __restrict__ Wout, const float* __restrict__ h0,
    const float* __restrict__ c0, float* __restrict__ hbuf,
    float* __restrict__ featsP, int* __restrict__ ctr) {
  __shared__ __align__(16) float hshS[4 * 288];  // h staging, kc-swizzled
  __shared__ float hloc[4 * 33];                 // this step's h for feats
  __shared__ float WoL[16 * 33];                 // Wout slice

  int blk = blockIdx.x;
  int d = blk >> 8;
  int bg = (blk >> 3) & 31;
  int sl = blk & 7;
  int bbase = bg * 4;
  int tid = threadIdx.x;
  int u = tid >> 3, kc = tid & 7;
  int uglob = sl * 32 + u;
  int* tagsg = ctr + (d * 32 + bg) * 256 + 64;   // tags[sl] = last finished step + 1

  for (int i = tid; i < 16 * 32; i += 256) {
    int t = i >> 5, uu = i & 31;
    WoL[t * 33 + uu] = Wout[t * 512 + d * HH + sl * 32 + uu];
  }

  // Whh slice -> registers: wreg[kk] = Whh4[d][kc*32+kk][uglob] (i,f,g,o)
  float4 wreg[32];
  {
    const float4* Wd = Wg + (size_t)d * (HH * HH) + (size_t)(kc * 32) * HH + uglob;
#pragma unroll
    for (int kk = 0; kk < 32; ++kk) wreg[kk] = Wd[(size_t)kk * HH];
  }
  int b_own = ((kc & 1) << 1) | ((kc >> 1) & 1);
  float c_reg = c0[((size_t)d * BB + bbase + b_own) * HH + uglob];
  bool up0 = (kc & 1), up1 = (kc & 2);

  int sb = tid >> 6;
  int sk = (tid & 63) * 4;
  int ldoff = sb * 288 + (sk >> 5) * 36 + (sk & 31);

  for (int step = 0; step < SS; ++step) {
    int s = d ? (SS - 1 - step) : step;
    float4 xg = xp4[(((size_t)d * SS + s) * BB + bbase + b_own) * HH + uglob];

    float* ldst = &hshS[ldoff];
    if (step == 0) {
      const float* ps = h0 + ((size_t)d * BB + bbase + sb) * HH + sk;
      *(f32x4*)ldst = *(const f32x4*)ps;
    } else {
      i32x4 ta, tb;
      int m;
      do {
        load_tags8(tagsg, ta, tb);
        int m0 = min(min(ta[0], ta[1]), min(ta[2], ta[3]));
        int m1 = min(min(tb[0], tb[1]), min(tb[2], tb[3]));
        m = min(m0, m1);
      } while (m < step);
      const float* ps = hbuf + ((size_t)((step - 1) % 3) * 2 + d) * BB * HH +
                        (size_t)(bbase + sb) * HH + sk;
      *(f32x4*)ldst = load_f4_llc(ps);
    }
    __syncthreads();

    float4 a[4];
#pragma unroll
    for (int b = 0; b < 4; ++b) a[b] = make_float4(0.f, 0.f, 0.f, 0.f);
#pragma unroll
    for (int kk4 = 0; kk4 < 8; ++kk4) {
      float hvv[4][4];
#pragma unroll
      for (int b = 0; b < 4; ++b)
        *(f32x4*)&hvv[b][0] = *(const f32x4*)&hshS[b * 288 + kc * 36 + kk4 * 4];
#pragma unroll
      for (int j = 0; j < 4; ++j) {
        float4 w = wreg[kk4 * 4 + j];
#pragma unroll
        for (int b = 0; b < 4; ++b) {
          float hj = hvv[b][j];
          a[b].x += w.x * hj; a[b].y += w.y * hj;
          a[b].z += w.z * hj; a[b].w += w.w * hj;
        }
      }
    }

#pragma unroll
    for (int j = 0; j < 2; ++j) {
      float4 snd = up0 ? a[j] : a[j + 2];
      float4 rcv = shfl_xor4(snd, 1);
      if (!up0) add4(a[j], rcv); else add4(a[j + 2], rcv);
    }
    float4 v0 = up0 ? a[2] : a[0];
    float4 v1 = up0 ? a[3] : a[1];
    {
      float4 snd = up1 ? v0 : v1;
      float4 rcv = shfl_xor4(snd, 2);
      if (!up1) add4(v0, rcv); else add4(v1, rcv);
    }
    float4 keep = up1 ? v1 : v0;
    {
      float4 rcv = shfl_xor4(keep, 4);
      add4(keep, rcv);
    }

    float ii = keep.x + xg.x, ff = keep.y + xg.y;
    float gg = keep.z + xg.z, oo = keep.w + xg.w;
    c_reg = sigm(ff) * c_reg + sigm(ii) * tanhf(gg);
    float hn = sigm(oo) * tanhf(c_reg);

    if (kc < 4) {
      __hip_atomic_store(
          &hbuf[((size_t)(step % 3) * 2 + d) * BB * HH + (size_t)(bbase + b_own) * HH + uglob],
          hn, __ATOMIC_RELAXED, __HIP_MEMORY_SCOPE_AGENT);
      hloc[b_own * 33 + u] = hn;
    }
    __syncthreads();   // drains vmcnt(0) per wave -> all h stores at LLC

    if (tid == 0)
      __hip_atomic_store(&tagsg[sl], step + 1, __ATOMIC_RELAXED,
                         __HIP_MEMORY_SCOPE_AGENT);

    {
      int b2 = tid >> 6, t = (tid >> 2) & 15, pr = tid & 3;
      float p = 0.f;
#pragma unroll
      for (int q = 0; q < 8; ++q)
        p += hloc[b2 * 33 + pr * 8 + q] * WoL[t * 33 + pr * 8 + q];
      p += __shfl_xor(p, 1);
      p += __shfl_xor(p, 2);
      if (pr == 0)
        featsP[(((size_t)(d * 8 + sl) * BB + bbase + b2) * SS + s) * TT + t] = p;
    }
  }
}

// ---------------- feats slice reduction ----------------
__global__ void k_fsum(const float* __restrict__ featsP, float* __restrict__ featsF) {
  int b = blockIdx.x;
  int tid = threadIdx.x;
  float acc[8];
#pragma unroll
  for (int j = 0; j < 8; ++j) acc[j] = 0.f;
  for (int dsl = 0; dsl < 16; ++dsl) {
    const float* fp = featsP + ((size_t)dsl * BB + b) * (SS * TT);
#pragma unroll
    for (int j = 0; j < 8; ++j) acc[j] += fp[j * 256 + tid];
  }
  float* fo = featsF + (size_t)b * (SS * TT);
#pragma unroll
  for (int j = 0; j < 8; ++j) fo[j * 256 + tid] = acc[j];
}

// ---------------- Viterbi (LDS backpointers + next-feat prefetch) ----------------
__global__ void k_viterbi(const float* __restrict__ featsF, const float* __restrict__ b_out,
                          const float* __restrict__ trans, float* __restrict__ out) {
  __shared__ float tr[TT * TT];
  __shared__ unsigned char bpl[16][SS][TT];   // 32 KB
  int tid = threadIdx.x;
  if (tid < TT * TT) tr[tid] = trans[tid];
  __syncthreads();

  int bg = tid >> 4;
  int next = tid & 15;
  int b = blockIdx.x * 16 + bg;
  float fv = (next == START_TAG) ? 0.0f : NEGV;
  float bo = b_out[next];
  const float* fF = featsF + (size_t)b * SS * TT;

  // prefetch step-0 feat; each iteration prefetches s+1 before the serial
  // shuffle reduction of s, hiding the ~300-cycle L2 latency.
  float feat_cur = fF[next];
  for (int s = 0; s < SS; ++s) {
    float feat_next = (s + 1 < SS) ? fF[(s + 1) * TT + next] : 0.f;
    float best = -INFINITY; int arg = 0;
#pragma unroll
    for (int prev = 0; prev < TT; ++prev) {
      float fvp = __shfl(fv, prev, 16);
      float cand = fvp + tr[next * TT + prev];
      if (cand > best) { best = cand; arg = prev; }
    }
    fv = best + feat_cur + bo;
    bpl[bg][s][next] = (unsigned char)arg;
    feat_cur = feat_next;
  }

  float bv = fv + tr[STOP_TAG * TT + next];
  int bi = next;
#pragma unroll
  for (int off = 8; off; off >>= 1) {
    float ov = __shfl_down(bv, off, 16);
    int oi = __shfl_down(bi, off, 16);
    if (ov > bv || (ov == bv && oi < bi)) { bv = ov; bi = oi; }
  }
  if (next == 0) {
    out[b] = bv;
    int tag = bi;
    float* po = out + BB + (size_t)b * SS;
    for (int s = SS - 1; s >= 0; --s) {
      po[s] = (float)tag;
      tag = bpl[bg][s][tag];
    }
  }
}

// ---------------- host ----------------
extern "C" void kernel_launch(void* const* d_in, const int* in_sizes, int n_in,
                              void* d_out, int out_size, void* d_ws, size_t ws_size,
                              hipStream_t stream) {
  const int*   sent  = (const int*)d_in[0];
  const float* emb   = (const float*)d_in[1];
  const float* Wih_f = (const float*)d_in[2];
  const float* Whh_f = (const float*)d_in[3];
  const float* bih_f = (const float*)d_in[4];
  const float* bhh_f = (const float*)d_in[5];
  const float* Wih_b = (const float*)d_in[6];
  const float* Whh_b = (const float*)d_in[7];
  const float* bih_b = (const float*)d_in[8];
  const float* bhh_b = (const float*)d_in[9];
  const float* Wout  = (const float*)d_in[10];
  const float* b_out = (const float*)d_in[11];
  const float* trans = (const float*)d_in[12];
  const float* h0    = (const float*)d_in[13];
  const float* c0    = (const float*)d_in[14];

  float* ws = (float*)d_ws;
  size_t off = 0;
  float* xproj  = ws + off; off += (size_t)2 * SS * BB * G4;          // 33,554,432 fl
  float* WihT   = ws + off; off += (size_t)2 * EE * G4;               //    614,400
  float* Whh4   = ws + off; off += (size_t)2 * HH * G4;               //    524,288
  float* bsum   = ws + off; off += (size_t)2 * G4;                    //      2,048
  float* featsP = ws + off; off += (size_t)16 * BB * SS * TT;         //  4,194,304
  float* featsF = ws + off; off += (size_t)BB * SS * TT;              //    262,144
  float* hbuf   = ws + off; off += (size_t)3 * 2 * BB * HH;           //    196,608
  int*   ctr    = (int*)(ws + off); off += 64 * 256;                  //     64 KB

  const int NPREP = 2 * EE * G4 + 2 * HH * G4 + 2 * G4 + 64 * 256;
  k_prep<<<(NPREP + 255) / 256, 256, 0, stream>>>(Wih_f, Whh_f, bih_f, bhh_f,
                                                  Wih_b, Whh_b, bih_b, bhh_b,
                                                  WihT, Whh4, bsum, ctr);
  k_xproj<<<1024, 256, 0, stream>>>(sent, emb, WihT, bsum, (float4*)xproj);

  // plain launch: 512 blocks at 2/CU (capacity-guaranteed) -> all co-resident
  k_recur<<<512, 256, 0, stream>>>((const float4*)xproj, (const float4*)Whh4,
                                   Wout, h0, c0, hbuf, featsP, ctr);

  k_fsum<<<BB, 256, 0, stream>>>(featsP, featsF);
  k_viterbi<<<8, 256, 0, stream>>>(featsF, b_out, trans, (float*)d_out);
}